// Round 1
// baseline (435.060 us; speedup 1.0000x reference)
//
#include <hip/hip_runtime.h>
#include <stdint.h>

// CoarseMatching on MI355X.
// conf[n,l,s] = softmax_l(sim) * softmax_s(sim), sim = <f0[l],f1[s]>/(256*0.1).
// No max-subtraction needed: |sim| <= ~4 for N(0,1) features, exp() safe in fp32.
// den_row[l] = sum_s exp(sim), den_col[s] = sum_l exp(sim),
// conf = exp(2*sim) / (den_row*den_col).
// Passes: cast->f16 | row-stats GEMM | col-stats GEMM (swapped operands) |
//         invert dens | conf GEMM (writes conf + rowmax/argmax + colmax partials) |
//         colmax merge | finalize (mask_v / j_ids / mconf).

typedef _Float16 f16;
typedef _Float16 f16x8 __attribute__((ext_vector_type(8)));
typedef float f32x4 __attribute__((ext_vector_type(4)));

#define N_B 4
#define L_DIM 3600
#define S_DIM 3600
#define C_DIM 256
#define BM 48          // rows per block (3 waves x 16)
#define BN 48          // cols per s-iteration
#define WAVES 3
#define NTHREADS 192
#define CHUNK_COLS 720 // S split into 5 chunks for occupancy
#define CHUNK_ITERS 15 // 720/48
#define NCHUNKS 5
#define NRT 75         // 3600/48
#define YT_STRIDE 264  // 256 + 8 halfs pad (528B row stride, breaks bank conflicts)

// sim = dot/25.6 ; exp(sim) = exp2(dot * log2e/25.6)
#define C_EXP1 (0.0390625f * 1.4426950408889634f)
#define C_EXP2 (2.0f * 0.0390625f * 1.4426950408889634f)

__global__ void cast_kernel(const float* __restrict__ a, const float* __restrict__ b,
                            f16* __restrict__ ah, f16* __restrict__ bh, int total8) {
  int i = blockIdx.x * blockDim.x + threadIdx.x;
  if (i >= total8) return;
  const float4* a4 = (const float4*)a;
  const float4* b4 = (const float4*)b;
  float4 x = a4[2 * (size_t)i], y = a4[2 * (size_t)i + 1];
  f16x8 o = {(f16)x.x, (f16)x.y, (f16)x.z, (f16)x.w,
             (f16)y.x, (f16)y.y, (f16)y.z, (f16)y.w};
  *(f16x8*)(ah + 8 * (size_t)i) = o;
  x = b4[2 * (size_t)i]; y = b4[2 * (size_t)i + 1];
  f16x8 o2 = {(f16)x.x, (f16)x.y, (f16)x.z, (f16)x.w,
              (f16)y.x, (f16)y.y, (f16)y.z, (f16)y.w};
  *(f16x8*)(bh + 8 * (size_t)i) = o2;
}

// den[row] += sum over this block's S-chunk of exp(sim[row, s])
__global__ __launch_bounds__(NTHREADS) void stats_kernel(
    const f16* __restrict__ X, const f16* __restrict__ Y, float* __restrict__ den) {
  __shared__ f16 Yt[BN][YT_STRIDE];
  const int rt = blockIdx.x, ch = blockIdx.y, n = blockIdx.z;
  const int tid = threadIdx.x;
  const int wave = tid >> 6, lane = tid & 63;
  const int q = lane >> 4, r = lane & 15;
  const int l0 = rt * BM;
  const int s0 = ch * CHUNK_COLS;

  // A fragments: full K=256 in registers, reused across the whole chunk sweep.
  // Layout per 16x16x32 f16 MFMA: A[m=lane&15][k=(lane>>4)*8 + j], contiguous 16B.
  f16x8 a[8];
  {
    const f16* xrow = X + ((size_t)n * L_DIM + l0 + wave * 16 + r) * C_DIM;
#pragma unroll
    for (int k = 0; k < 8; ++k) a[k] = *(const f16x8*)(xrow + k * 32 + q * 8);
  }

  float sum_e[4] = {0.f, 0.f, 0.f, 0.f};

  for (int it = 0; it < CHUNK_ITERS; ++it) {
    const f16* ysrc = Y + ((size_t)n * S_DIM + s0 + it * BN) * C_DIM;
#pragma unroll
    for (int i = 0; i < 8; ++i) {  // 1536 chunks of 16B, 192 threads x 8
      int c = i * NTHREADS + tid;
      int row = c >> 5, cc = c & 31;
      *(f16x8*)&Yt[row][cc * 8] = *(const f16x8*)(ysrc + row * C_DIM + cc * 8);
    }
    __syncthreads();

    f32x4 acc[3];
#pragma unroll
    for (int t = 0; t < 3; ++t) acc[t] = (f32x4){0.f, 0.f, 0.f, 0.f};
#pragma unroll
    for (int nt = 0; nt < 3; ++nt) {
#pragma unroll
      for (int k = 0; k < 8; ++k) {
        f16x8 b = *(const f16x8*)&Yt[nt * 16 + r][k * 32 + q * 8];
        acc[nt] = __builtin_amdgcn_mfma_f32_16x16x32_f16(a[k], b, acc[nt], 0, 0, 0);
      }
    }
    __syncthreads();

    // C/D layout: col = lane&15 (the s index), row = (lane>>4)*4 + reg (the l index)
#pragma unroll
    for (int nt = 0; nt < 3; ++nt)
#pragma unroll
      for (int g = 0; g < 4; ++g) sum_e[g] += exp2f(acc[nt][g] * C_EXP1);
  }

  // reduce the 16 lanes (different s columns, same 4 rows)
#pragma unroll
  for (int m = 1; m < 16; m <<= 1)
#pragma unroll
    for (int g = 0; g < 4; ++g) sum_e[g] += __shfl_xor(sum_e[g], m, 64);
  if (r == 0) {
#pragma unroll
    for (int g = 0; g < 4; ++g)
      atomicAdd(&den[n * L_DIM + l0 + wave * 16 + q * 4 + g], sum_e[g]);
  }
}

__global__ void invert_kernel(float* __restrict__ a, float* __restrict__ b) {
  int i = blockIdx.x * blockDim.x + threadIdx.x;
  if (i >= N_B * L_DIM) return;
  a[i] = 1.0f / a[i];
  b[i] = 1.0f / b[i];
}

__global__ __launch_bounds__(NTHREADS) void conf_kernel(
    const f16* __restrict__ X, const f16* __restrict__ Y,
    const float* __restrict__ invdr, const float* __restrict__ invdc,
    float* __restrict__ conf_out, unsigned long long* __restrict__ rowarg,
    float* __restrict__ colpart) {
  __shared__ f16 Yt[BN][YT_STRIDE];
  __shared__ float cmax_w[WAVES][CHUNK_COLS];
  const int rt = blockIdx.x, ch = blockIdx.y, n = blockIdx.z;
  const int tid = threadIdx.x;
  const int wave = tid >> 6, lane = tid & 63;
  const int q = lane >> 4, r = lane & 15;
  const int l0 = rt * BM;
  const int s0 = ch * CHUNK_COLS;

  f16x8 a[8];
  {
    const f16* xrow = X + ((size_t)n * L_DIM + l0 + wave * 16 + r) * C_DIM;
#pragma unroll
    for (int k = 0; k < 8; ++k) a[k] = *(const f16x8*)(xrow + k * 32 + q * 8);
  }
  float idr[4];
#pragma unroll
  for (int g = 0; g < 4; ++g)
    idr[g] = invdr[n * L_DIM + l0 + wave * 16 + q * 4 + g];

  float rmax[4] = {0.f, 0.f, 0.f, 0.f};
  int rj[4] = {0, 0, 0, 0};

  for (int it = 0; it < CHUNK_ITERS; ++it) {
    const f16* ysrc = Y + ((size_t)n * S_DIM + s0 + it * BN) * C_DIM;
#pragma unroll
    for (int i = 0; i < 8; ++i) {
      int c = i * NTHREADS + tid;
      int row = c >> 5, cc = c & 31;
      *(f16x8*)&Yt[row][cc * 8] = *(const f16x8*)(ysrc + row * C_DIM + cc * 8);
    }
    __syncthreads();

    f32x4 acc[3];
#pragma unroll
    for (int t = 0; t < 3; ++t) acc[t] = (f32x4){0.f, 0.f, 0.f, 0.f};
#pragma unroll
    for (int nt = 0; nt < 3; ++nt) {
#pragma unroll
      for (int k = 0; k < 8; ++k) {
        f16x8 b = *(const f16x8*)&Yt[nt * 16 + r][k * 32 + q * 8];
        acc[nt] = __builtin_amdgcn_mfma_f32_16x16x32_f16(a[k], b, acc[nt], 0, 0, 0);
      }
    }
    __syncthreads();

#pragma unroll
    for (int nt = 0; nt < 3; ++nt) {
      int scol = s0 + it * BN + nt * 16 + r;
      float idc = invdc[n * S_DIM + scol];
      float cm = 0.f;
#pragma unroll
      for (int g = 0; g < 4; ++g) {
        float v = exp2f(acc[nt][g] * C_EXP2) * idr[g] * idc;
        int lrow = l0 + wave * 16 + q * 4 + g;
        conf_out[((size_t)n * L_DIM + lrow) * S_DIM + scol] = v;
        if (v > rmax[g]) { rmax[g] = v; rj[g] = scol; }  // strict > keeps first s
        cm = fmaxf(cm, v);
      }
      // column max across the 4 quads holding this column
      cm = fmaxf(cm, __shfl_xor(cm, 16, 64));
      cm = fmaxf(cm, __shfl_xor(cm, 32, 64));
      if (q == 0) cmax_w[wave][it * BN + nt * 16 + r] = cm;  // each col written once
    }
  }

  // row max/argmax: reduce over the 16 s-lanes; smaller s wins ties
#pragma unroll
  for (int m = 1; m < 16; m <<= 1) {
#pragma unroll
    for (int g = 0; g < 4; ++g) {
      float ov = __shfl_xor(rmax[g], m, 64);
      int oj = __shfl_xor(rj[g], m, 64);
      if (ov > rmax[g] || (ov == rmax[g] && oj < rj[g])) { rmax[g] = ov; rj[g] = oj; }
    }
  }
  if (r == 0) {
#pragma unroll
    for (int g = 0; g < 4; ++g) {
      // pack (float bits, ~idx): atomicMax picks larger conf, then SMALLER s on tie
      unsigned long long key =
          ((unsigned long long)__float_as_uint(rmax[g]) << 32) |
          (unsigned int)(~(unsigned int)rj[g]);
      atomicMax(&rowarg[n * L_DIM + l0 + wave * 16 + q * 4 + g], key);
    }
  }

  __syncthreads();
  for (int i = tid; i < CHUNK_COLS; i += NTHREADS) {
    float p = fmaxf(fmaxf(cmax_w[0][i], cmax_w[1][i]), cmax_w[2][i]);
    colpart[((size_t)n * NRT + rt) * S_DIM + s0 + i] = p;
  }
}

__global__ void colmerge_kernel(const float* __restrict__ colpart,
                                float* __restrict__ colmax) {
  int i = blockIdx.x * blockDim.x + threadIdx.x;
  if (i >= N_B * S_DIM) return;
  int n = i / S_DIM, s = i - n * S_DIM;
  float m = 0.f;
  for (int rt = 0; rt < NRT; ++rt)
    m = fmaxf(m, colpart[((size_t)n * NRT + rt) * S_DIM + s]);
  colmax[i] = m;
}

__global__ void finalize_kernel(const unsigned long long* __restrict__ rowarg,
                                const float* __restrict__ colmax,
                                const int* __restrict__ h0c, const int* __restrict__ w0c,
                                const int* __restrict__ h1c, const int* __restrict__ w1c,
                                float* __restrict__ out_maskv, float* __restrict__ out_jids,
                                float* __restrict__ out_mconf) {
  int i = blockIdx.x * blockDim.x + threadIdx.x;
  if (i >= N_B * L_DIM) return;
  int n = i / L_DIM, l = i - n * L_DIM;
  unsigned long long key = rowarg[i];
  float rm = __uint_as_float((unsigned int)(key >> 32));
  int j = (int)(~(unsigned int)key);
  int W0 = *w0c, H0 = *h0c, W1 = *w1c, H1 = *h1c;
  int li = l / W0, lj = l - li * W0;
  bool vl = (li >= 2) && (li < H0 - 2) && (lj >= 2) && (lj < W0 - 2);
  int si = j / W1, sj = j - si * W1;
  bool vs = (si >= 2) && (si < H1 - 2) && (sj >= 2) && (sj < W1 - 2);
  float cm = colmax[n * S_DIM + j];
  bool mv = (rm > 0.2f) && vl && vs &&
            (__float_as_uint(rm) == __float_as_uint(cm));
  out_maskv[i] = mv ? 1.0f : 0.0f;
  out_jids[i]  = mv ? (float)j : 0.0f;
  out_mconf[i] = mv ? rm : 0.0f;
}

extern "C" void kernel_launch(void* const* d_in, const int* in_sizes, int n_in,
                              void* d_out, int out_size, void* d_ws, size_t ws_size,
                              hipStream_t stream) {
  const float* f0 = (const float*)d_in[0];
  const float* f1 = (const float*)d_in[1];
  const int* h0c = (const int*)d_in[2];
  const int* w0c = (const int*)d_in[3];
  const int* h1c = (const int*)d_in[4];
  const int* w1c = (const int*)d_in[5];

  char* ws = (char*)d_ws;
  size_t o = 0;
  f16* f0h = (f16*)(ws + o);               o += (size_t)N_B * L_DIM * C_DIM * 2;  // 7.37MB
  f16* f1h = (f16*)(ws + o);               o += (size_t)N_B * S_DIM * C_DIM * 2;  // 7.37MB
  float* den_r = (float*)(ws + o);         o += (size_t)N_B * L_DIM * 4;
  float* den_c = (float*)(ws + o);         o += (size_t)N_B * S_DIM * 4;
  unsigned long long* rowarg = (unsigned long long*)(ws + o); o += (size_t)N_B * L_DIM * 8;
  float* colmax = (float*)(ws + o);        o += (size_t)N_B * S_DIM * 4;
  float* colpart = (float*)(ws + o);       o += (size_t)N_B * NRT * S_DIM * 4;    // 4.32MB
  // total ~19.4 MB of ws

  float* conf = (float*)d_out;
  float* out_maskv = conf + (size_t)N_B * L_DIM * S_DIM;
  float* out_jids = out_maskv + N_B * L_DIM;
  float* out_mconf = out_jids + N_B * L_DIM;

  hipMemsetAsync(den_r, 0, (size_t)N_B * L_DIM * 4, stream);
  hipMemsetAsync(den_c, 0, (size_t)N_B * S_DIM * 4, stream);
  hipMemsetAsync(rowarg, 0, (size_t)N_B * L_DIM * 8, stream);

  int total8 = N_B * L_DIM * C_DIM / 8;  // 460800
  cast_kernel<<<dim3((total8 + 255) / 256), 256, 0, stream>>>(f0, f1, f0h, f1h, total8);

  dim3 grid(NRT, NCHUNKS, N_B);
  stats_kernel<<<grid, NTHREADS, 0, stream>>>(f0h, f1h, den_r);  // den_row
  stats_kernel<<<grid, NTHREADS, 0, stream>>>(f1h, f0h, den_c);  // den_col
  invert_kernel<<<(N_B * L_DIM + 255) / 256, 256, 0, stream>>>(den_r, den_c);
  conf_kernel<<<grid, NTHREADS, 0, stream>>>(f0h, f1h, den_r, den_c, conf, rowarg, colpart);
  colmerge_kernel<<<(N_B * S_DIM + 255) / 256, 256, 0, stream>>>(colpart, colmax);
  finalize_kernel<<<(N_B * L_DIM + 255) / 256, 256, 0, stream>>>(
      rowarg, colmax, h0c, w0c, h1c, w1c, out_maskv, out_jids, out_mconf);
}

// Round 2
// 414.423 us; speedup vs baseline: 1.0498x; 1.0498x over previous
//
#include <hip/hip_runtime.h>
#include <stdint.h>

// CoarseMatching on MI355X, round 2.
// conf[n,l,s] = softmax_l(sim)*softmax_s(sim), sim = <f0[l],f1[s]>/25.6.
// |sim| <= ~4 so exp() is safe in fp32 without max subtraction.
// Pass A (GEMM, fused): e = exp(sim) stored f16 to ws; den_r[l] = sum_s e,
//   den_c[s] = sum_l e accumulated in the same pass.
// Pass B (streaming): conf = e^2 * (1/den_r) * (1/den_c); rowmax/argmax via
//   packed u64 atomicMax; colmax via per-block partials + merge.
// Then finalize: threshold/border/mutual-nearest -> mask_v, j_ids, mconf.

typedef _Float16 f16;
typedef _Float16 f16x8 __attribute__((ext_vector_type(8)));
typedef _Float16 f16x4 __attribute__((ext_vector_type(4)));
typedef float f32x4 __attribute__((ext_vector_type(4)));

#define N_B 4
#define L_DIM 3600
#define S_DIM 3600
#define C_DIM 256

// Pass A tiling: 3 waves x 48 rows = 144 rows/block; 48 cols/iter; 720-col chunks.
#define P1_THREADS 192
#define P1_BM 144
#define P1_BN 48
#define P1_ITERS 15
#define P1_CHUNK 720
#define P1_NCH 5
#define P1_NRT 25        // 3600/144
#define YT_STRIDE 264    // 256 + 8 halfs pad

// Pass B tiling: 48 rows/block, 4 waves each owning a 900-col strip.
#define P2_ROWS 48
#define P2_NRT 75        // 3600/48

// sim = dot/25.6 ; exp(sim) = exp2(dot * log2e/25.6)
#define C_EXP1 (0.0390625f * 1.4426950408889634f)

__global__ void cast_kernel(const float* __restrict__ a, const float* __restrict__ b,
                            f16* __restrict__ ah, f16* __restrict__ bh, int total8) {
  int i = blockIdx.x * blockDim.x + threadIdx.x;
  if (i >= total8) return;
  const float4* a4 = (const float4*)a;
  const float4* b4 = (const float4*)b;
  float4 x = a4[2 * (size_t)i], y = a4[2 * (size_t)i + 1];
  f16x8 o = {(f16)x.x, (f16)x.y, (f16)x.z, (f16)x.w,
             (f16)y.x, (f16)y.y, (f16)y.z, (f16)y.w};
  *(f16x8*)(ah + 8 * (size_t)i) = o;
  x = b4[2 * (size_t)i]; y = b4[2 * (size_t)i + 1];
  f16x8 o2 = {(f16)x.x, (f16)x.y, (f16)x.z, (f16)x.w,
              (f16)y.x, (f16)y.y, (f16)y.z, (f16)y.w};
  *(f16x8*)(bh + 8 * (size_t)i) = o2;
}

// Fused GEMM: writes e=exp(sim) f16 and accumulates den_r (rows) + den_c (cols).
__global__ __launch_bounds__(P1_THREADS) void gemm_stats_kernel(
    const f16* __restrict__ X, const f16* __restrict__ Y,
    f16* __restrict__ eh, float* __restrict__ den_r, float* __restrict__ den_c) {
  __shared__ f16 Yt[P1_BN][YT_STRIDE];
  __shared__ float colsum_w[3][P1_CHUNK];
  const int rt = blockIdx.x, ch = blockIdx.y, n = blockIdx.z;
  const int tid = threadIdx.x;
  const int wave = tid >> 6, lane = tid & 63;
  const int q = lane >> 4, r = lane & 15;
  const int l0 = rt * P1_BM;
  const int s0 = ch * P1_CHUNK;

  // A fragments: 48 rows (3 groups of 16) x K=256 in registers.
  f16x8 a[3][8];
#pragma unroll
  for (int grp = 0; grp < 3; ++grp) {
    const f16* xrow = X + ((size_t)n * L_DIM + l0 + wave * 48 + grp * 16 + r) * C_DIM;
#pragma unroll
    for (int k = 0; k < 8; ++k) a[grp][k] = *(const f16x8*)(xrow + k * 32 + q * 8);
  }

  float sum_e[3][4];
#pragma unroll
  for (int grp = 0; grp < 3; ++grp)
#pragma unroll
    for (int g = 0; g < 4; ++g) sum_e[grp][g] = 0.f;

  // iteration-invariant e-store row offsets
  const f16* ebase = eh + ((size_t)n * L_DIM + l0 + wave * 48) * S_DIM;

  for (int it = 0; it < P1_ITERS; ++it) {
    const f16* ysrc = Y + ((size_t)n * S_DIM + s0 + it * P1_BN) * C_DIM;
#pragma unroll
    for (int i = 0; i < 8; ++i) {  // 48*32=1536 16B chunks, 192 thr x 8
      int c = i * P1_THREADS + tid;
      int row = c >> 5, cc = c & 31;
      *(f16x8*)&Yt[row][cc * 8] = *(const f16x8*)(ysrc + row * C_DIM + cc * 8);
    }
    __syncthreads();

    f32x4 acc[3][3];  // [grp][nt]
#pragma unroll
    for (int grp = 0; grp < 3; ++grp)
#pragma unroll
      for (int nt = 0; nt < 3; ++nt) acc[grp][nt] = (f32x4){0.f, 0.f, 0.f, 0.f};

    // k outer, nt mid, grp inner: same-acc reuse distance 9 MFMAs
#pragma unroll
    for (int k = 0; k < 8; ++k) {
#pragma unroll
      for (int nt = 0; nt < 3; ++nt) {
        f16x8 b = *(const f16x8*)&Yt[nt * 16 + r][k * 32 + q * 8];
#pragma unroll
        for (int grp = 0; grp < 3; ++grp)
          acc[grp][nt] = __builtin_amdgcn_mfma_f32_16x16x32_f16(a[grp][k], b, acc[grp][nt], 0, 0, 0);
      }
    }
    __syncthreads();

    // epilogue: C/D layout col=lane&15, row=(lane>>4)*4+reg
#pragma unroll
    for (int nt = 0; nt < 3; ++nt) {
      int scol = s0 + it * P1_BN + nt * 16 + r;
      float csum = 0.f;
#pragma unroll
      for (int grp = 0; grp < 3; ++grp) {
#pragma unroll
        for (int g = 0; g < 4; ++g) {
          float e = exp2f(acc[grp][nt][g] * C_EXP1);
          sum_e[grp][g] += e;
          csum += e;
          ((f16*)ebase)[(size_t)(grp * 16 + q * 4 + g) * S_DIM + scol] = (f16)e;
        }
      }
      csum += __shfl_xor(csum, 16, 64);
      csum += __shfl_xor(csum, 32, 64);
      if (q == 0) colsum_w[wave][it * P1_BN + nt * 16 + r] = csum;
    }
  }

  // row sums: reduce over the 16 s-lanes
#pragma unroll
  for (int m = 1; m < 16; m <<= 1)
#pragma unroll
    for (int grp = 0; grp < 3; ++grp)
#pragma unroll
      for (int g = 0; g < 4; ++g) sum_e[grp][g] += __shfl_xor(sum_e[grp][g], m, 64);
  if (r == 0) {
#pragma unroll
    for (int grp = 0; grp < 3; ++grp)
#pragma unroll
      for (int g = 0; g < 4; ++g)
        atomicAdd(&den_r[n * L_DIM + l0 + wave * 48 + grp * 16 + q * 4 + g], sum_e[grp][g]);
  }

  __syncthreads();
  for (int i = tid; i < P1_CHUNK; i += P1_THREADS)
    atomicAdd(&den_c[n * S_DIM + s0 + i],
              colsum_w[0][i] + colsum_w[1][i] + colsum_w[2][i]);
}

__global__ void invert_kernel(float* __restrict__ a, float* __restrict__ b) {
  int i = blockIdx.x * blockDim.x + threadIdx.x;
  if (i >= N_B * L_DIM) return;
  a[i] = 1.0f / a[i];
  b[i] = 1.0f / b[i];
}

// Streaming conf pass: 48 rows/block, wave w owns cols [w*900, w*900+900).
__global__ __launch_bounds__(256) void conf_kernel(
    const f16* __restrict__ eh, const float* __restrict__ invdr,
    const float* __restrict__ invdc, float* __restrict__ conf_out,
    unsigned long long* __restrict__ rowarg, float* __restrict__ colpart) {
  const int rt = blockIdx.x, n = blockIdx.y;
  const int tid = threadIdx.x;
  const int wave = tid >> 6, lane = tid & 63;
  const int l0 = rt * P2_ROWS;

  // per-lane column chunks: chunk = ci*64+lane within this wave's 225 4-col chunks
  int colb[4];
  bool cv[4];
  float4 idc4[4];
  float4 cp[4];
#pragma unroll
  for (int ci = 0; ci < 4; ++ci) {
    int chunk = ci * 64 + lane;
    cv[ci] = chunk < 225;
    colb[ci] = (wave * 225 + (chunk < 225 ? chunk : 0)) * 4;
    idc4[ci] = *(const float4*)(invdc + n * S_DIM + colb[ci]);
    cp[ci] = (float4){0.f, 0.f, 0.f, 0.f};
  }

  for (int row = 0; row < P2_ROWS; ++row) {
    const int l = l0 + row;
    const f16* erow = eh + ((size_t)n * L_DIM + l) * S_DIM;
    float* crow = conf_out + ((size_t)n * L_DIM + l) * S_DIM;
    const float idr = invdr[n * L_DIM + l];
    float mx = 0.f;
    int mj = 0;
#pragma unroll
    for (int ci = 0; ci < 4; ++ci) {
      if (cv[ci]) {
        f16x4 e4 = *(const f16x4*)(erow + colb[ci]);
        float e0 = (float)e4.x, e1 = (float)e4.y, e2 = (float)e4.z, e3 = (float)e4.w;
        float4 w;
        w.x = e0 * e0 * idr * idc4[ci].x;
        w.y = e1 * e1 * idr * idc4[ci].y;
        w.z = e2 * e2 * idr * idc4[ci].z;
        w.w = e3 * e3 * idr * idc4[ci].w;
        *(float4*)(crow + colb[ci]) = w;
        int c0 = colb[ci];
        if (w.x > mx) { mx = w.x; mj = c0; }
        if (w.y > mx) { mx = w.y; mj = c0 + 1; }
        if (w.z > mx) { mx = w.z; mj = c0 + 2; }
        if (w.w > mx) { mx = w.w; mj = c0 + 3; }
        cp[ci].x = fmaxf(cp[ci].x, w.x);
        cp[ci].y = fmaxf(cp[ci].y, w.y);
        cp[ci].z = fmaxf(cp[ci].z, w.z);
        cp[ci].w = fmaxf(cp[ci].w, w.w);
      }
    }
    // reduce (mx, mj) across 64 lanes; larger mx wins, tie -> smaller mj
#pragma unroll
    for (int m = 1; m < 64; m <<= 1) {
      float ov = __shfl_xor(mx, m, 64);
      int oj = __shfl_xor(mj, m, 64);
      if (ov > mx || (ov == mx && oj < mj)) { mx = ov; mj = oj; }
    }
    if (lane == 0) {
      unsigned long long key =
          ((unsigned long long)__float_as_uint(mx) << 32) |
          (unsigned int)(~(unsigned int)mj);
      atomicMax(&rowarg[n * L_DIM + l], key);
    }
  }

  float* cpo = colpart + ((size_t)n * P2_NRT + rt) * S_DIM;
#pragma unroll
  for (int ci = 0; ci < 4; ++ci)
    if (cv[ci]) *(float4*)(cpo + colb[ci]) = cp[ci];
}

__global__ void colmerge_kernel(const float* __restrict__ colpart,
                                float* __restrict__ colmax) {
  int i = blockIdx.x * blockDim.x + threadIdx.x;
  if (i >= N_B * S_DIM) return;
  int n = i / S_DIM, s = i - n * S_DIM;
  float m = 0.f;
  for (int rt = 0; rt < P2_NRT; ++rt)
    m = fmaxf(m, colpart[((size_t)n * P2_NRT + rt) * S_DIM + s]);
  colmax[i] = m;
}

__global__ void finalize_kernel(const unsigned long long* __restrict__ rowarg,
                                const float* __restrict__ colmax,
                                const int* __restrict__ h0c, const int* __restrict__ w0c,
                                const int* __restrict__ h1c, const int* __restrict__ w1c,
                                float* __restrict__ out_maskv, float* __restrict__ out_jids,
                                float* __restrict__ out_mconf) {
  int i = blockIdx.x * blockDim.x + threadIdx.x;
  if (i >= N_B * L_DIM) return;
  int n = i / L_DIM, l = i - n * L_DIM;
  unsigned long long key = rowarg[i];
  float rm = __uint_as_float((unsigned int)(key >> 32));
  int j = (int)(~(unsigned int)key);
  int W0 = *w0c, H0 = *h0c, W1 = *w1c, H1 = *h1c;
  int li = l / W0, lj = l - li * W0;
  bool vl = (li >= 2) && (li < H0 - 2) && (lj >= 2) && (lj < W0 - 2);
  int si = j / W1, sj = j - si * W1;
  bool vs = (si >= 2) && (si < H1 - 2) && (sj >= 2) && (sj < W1 - 2);
  float cm = colmax[n * S_DIM + j];
  bool mv = (rm > 0.2f) && vl && vs &&
            (__float_as_uint(rm) == __float_as_uint(cm));
  out_maskv[i] = mv ? 1.0f : 0.0f;
  out_jids[i]  = mv ? (float)j : 0.0f;
  out_mconf[i] = mv ? rm : 0.0f;
}

extern "C" void kernel_launch(void* const* d_in, const int* in_sizes, int n_in,
                              void* d_out, int out_size, void* d_ws, size_t ws_size,
                              hipStream_t stream) {
  const float* f0 = (const float*)d_in[0];
  const float* f1 = (const float*)d_in[1];
  const int* h0c = (const int*)d_in[2];
  const int* w0c = (const int*)d_in[3];
  const int* h1c = (const int*)d_in[4];
  const int* w1c = (const int*)d_in[5];

  char* ws = (char*)d_ws;
  size_t o = 0;
  f16* f0h = (f16*)(ws + o);               o += (size_t)N_B * L_DIM * C_DIM * 2;   // 7.37MB
  f16* f1h = (f16*)(ws + o);               o += (size_t)N_B * S_DIM * C_DIM * 2;   // 7.37MB
  // zeroed region (one memset): den_r | den_c | rowarg
  float* den_r = (float*)(ws + o);         o += (size_t)N_B * L_DIM * 4;
  float* den_c = (float*)(ws + o);         o += (size_t)N_B * S_DIM * 4;
  unsigned long long* rowarg = (unsigned long long*)(ws + o); o += (size_t)N_B * L_DIM * 8;
  size_t zero_bytes = (size_t)N_B * L_DIM * (4 + 4 + 8);
  float* colmax = (float*)(ws + o);        o += (size_t)N_B * S_DIM * 4;
  float* colpart = (float*)(ws + o);       o += (size_t)N_B * P2_NRT * S_DIM * 4;  // 4.32MB
  f16* eh = (f16*)(ws + o);                o += (size_t)N_B * L_DIM * S_DIM * 2;   // 103.7MB

  float* conf = (float*)d_out;
  float* out_maskv = conf + (size_t)N_B * L_DIM * S_DIM;
  float* out_jids = out_maskv + N_B * L_DIM;
  float* out_mconf = out_jids + N_B * L_DIM;

  hipMemsetAsync(den_r, 0, zero_bytes, stream);

  int total8 = N_B * L_DIM * C_DIM / 8;  // 460800
  cast_kernel<<<dim3((total8 + 255) / 256), 256, 0, stream>>>(f0, f1, f0h, f1h, total8);

  dim3 g1(P1_NRT, P1_NCH, N_B);  // 25 x 5 x 4 = 500 blocks
  gemm_stats_kernel<<<g1, P1_THREADS, 0, stream>>>(f0h, f1h, eh, den_r, den_c);
  invert_kernel<<<(N_B * L_DIM + 255) / 256, 256, 0, stream>>>(den_r, den_c);
  dim3 g2(P2_NRT, N_B);          // 75 x 4 = 300 blocks
  conf_kernel<<<g2, 256, 0, stream>>>(eh, den_r, den_c, conf, rowarg, colpart);
  colmerge_kernel<<<(N_B * S_DIM + 255) / 256, 256, 0, stream>>>(colpart, colmax);
  finalize_kernel<<<(N_B * L_DIM + 255) / 256, 256, 0, stream>>>(
      rowarg, colmax, h0c, w0c, h1c, w1c, out_maskv, out_jids, out_mconf);
}